// Round 13
// baseline (1036.947 us; speedup 1.0000x reference)
//
#include <hip/hip_runtime.h>
#include <math.h>

#define DEVI __device__ __forceinline__
typedef unsigned short u16;
typedef unsigned int u32;
typedef unsigned char u8;
typedef float f32x4 __attribute__((ext_vector_type(4)));
typedef float fx4 __attribute__((ext_vector_type(4)));
typedef u32 ux4 __attribute__((ext_vector_type(4)));
typedef long lx2 __attribute__((ext_vector_type(2)));

static constexpr int CAP = 8192;   // per (router,rank,expert) list capacity

DEVI u16 f2b(float f) {            // f32 -> bf16 bits, RNE
  u32 x = __builtin_bit_cast(u32, f);
  u32 r = (x + 0x7fffu + ((x >> 16) & 1u)) >> 16;
  return (u16)r;
}
DEVI float b2f(u16 u) { return __builtin_bit_cast(float, (u32)u << 16); }

DEVI u32 f2fp8(float f) {          // f32 -> OCP e4m3fn, RNE, saturating (SW fallback)
  u32 x = __builtin_bit_cast(u32, f);
  u32 s = (x >> 24) & 0x80u;
  u32 ax = x & 0x7fffffffu;
  if (ax >= 0x43e80000u) return s | 0x7eu;
  if (ax < 0x3a800000u) return s;
  if (ax < 0x3c800000u) {
    float m = __builtin_bit_cast(float, ax) * 512.0f;
    return s | (u32)rintf(m);
  }
  u32 r = ax + 0x7ffffu + ((ax >> 20) & 1u);
  return s | (((r >> 23) - 120u) << 3) | ((r >> 20) & 7u);
}

#if __has_builtin(__builtin_amdgcn_cvt_pk_fp8_f32)
DEVI u32 pack4hw(float a, float b, float c, float d, float sc) {
  u32 lo = __builtin_amdgcn_cvt_pk_fp8_f32(a * sc, b * sc, 0, false);
  return (u32)__builtin_amdgcn_cvt_pk_fp8_f32(c * sc, d * sc, lo, true);
}
#else
DEVI u32 pack4hw(float a, float b, float c, float d, float sc) {
  return f2fp8(a * sc) | (f2fp8(b * sc) << 8) | (f2fp8(c * sc) << 16) | (f2fp8(d * sc) << 24);
}
#endif

DEVI void async16(const void* g, void* l) {
  __builtin_amdgcn_global_load_lds((const __attribute__((address_space(1))) void*)g,
                                   (__attribute__((address_space(3))) void*)l, 16, 0, 0);
}

// ---------------- f32 -> fp8(x1024), granule-interleaved, coalesced ----------------
// dest layout per 64B k-block: 16B chunk c = src granules {c, c+4} (granule = 8 elems).
// thread = one source float4 (coalesced 16B load); 4B store at permuted offset.
__global__ void cvt8_k(const float* __restrict__ s0, u8* __restrict__ d0,
                       const float* __restrict__ s1, u8* __restrict__ d1, long n) {
  long nq0 = n / 4, nq = nq0 * 2;                    // float4 count
  long stride = (long)gridDim.x * blockDim.x;
  for (long q = (long)blockIdx.x * blockDim.x + threadIdx.x; q < nq; q += stride) {
    long qi = q; const float* s = s0; u8* d = d0;
    if (qi >= nq0) { qi -= nq0; s = s1; d = d1; }
    fx4 v = __builtin_nontemporal_load((const fx4*)s + qi);
    u32 o = pack4hw(v.x, v.y, v.z, v.w, 1024.f);
    long b = qi >> 4; int s4 = (int)(qi & 15); int g = s4 >> 1;
    *(u32*)(d + b * 64 + 16 * (g & 3) + 8 * (g >> 2) + 4 * (s4 & 1)) = o;
  }
}

// ---------------- router phase 1: x_addr partials, k-split x2, 8 tok/block ----------------
__global__ __launch_bounds__(256) void xaddr2_k(
    const float* __restrict__ x, const float* __restrict__ Pw,
    double* __restrict__ xa_g, u8* __restrict__ xb) {
  __shared__ __align__(16) char sm[19584];
  float* xs  = (float*)sm;                     // [8][68]  f32
  float* pws = (float*)(sm + 2176);            // [64][68] f32

  const int tid = threadIdx.x;
  const int tok0 = blockIdx.x * 8;
  const int kbase = blockIdx.y * 512;
  const int tok = tid >> 5, dg = tid & 31;

  double a0 = 0, a1 = 0, a2 = 0, a3 = 0;

  const int rot0 = dg >> 3;
  const int rot1 = (dg >> 3) + 4;

  for (int kc = 0; kc < 8; ++kc) {
    const int k0 = kbase + kc * 64;
    if (tid < 128) {                           // stage x + emit fp8 interleaved
      int t = tid >> 4, c4 = tid & 15;
      size_t goff = (size_t)(tok0 + t) * 1024 + k0 + c4 * 4;
      fx4 v = __builtin_nontemporal_load((const fx4*)&x[goff]);
      *(fx4*)&xs[t * 68 + c4 * 4] = v;
      int g = c4 >> 1;
      int off = 16 * (g & 3) + 8 * (g >> 2) + 4 * (c4 & 1);
      u32 o8 = pack4hw(v.x, v.y, v.z, v.w, 1.0f);
      *(u32*)&xb[(size_t)(tok0 + t) * 1024 + k0 + off] = o8;
    }
#pragma unroll
    for (int j = 0; j < 4; ++j) {              // stage Pw, rotated chunk pos
      int f = tid + 256 * j;
      int pr = f >> 4, pc = f & 15;
      int pos = (pc + (pr >> 3)) & 15;
      *(float4*)&pws[pr * 68 + pos * 4] = *(const float4*)&Pw[(size_t)pr * 1024 + k0 + pc * 4];
    }
    __syncthreads();
    const float* xrow = &xs[tok * 68];
#pragma unroll
    for (int k4 = 0; k4 < 16; ++k4) {
      float4 xv = *(const float4*)&xrow[k4 * 4];
      float4 q0 = *(const float4*)&pws[dg * 68 + ((k4 + rot0) & 15) * 4];
      float4 q1 = *(const float4*)&pws[(dg + 32) * 68 + ((k4 + rot1) & 15) * 4];
      a0 += (double)xv.x * q0.x + (double)xv.y * q0.y;
      a1 += (double)xv.z * q0.z + (double)xv.w * q0.w;
      a2 += (double)xv.x * q1.x + (double)xv.y * q1.y;
      a3 += (double)xv.z * q1.z + (double)xv.w * q1.w;
    }
    __syncthreads();
  }

  size_t base = ((size_t)blockIdx.y * 8192 + (tok0 + tok)) * 64;
  xa_g[base + dg] = a0 + a1;
  xa_g[base + dg + 32] = a2 + a3;
}

// ---------------- router phase 2: z (f64), top3+softmax, lists, bias init ----------------
__global__ __launch_bounds__(256) void route2_k(
    const double* __restrict__ xa_g,
    const float* __restrict__ U1, const float* __restrict__ U2, const float* __restrict__ U3,
    const float* __restrict__ b2,
    int* __restrict__ cnt, int* __restrict__ ltok, float* __restrict__ lwgt,
    float* __restrict__ out) {
  __shared__ double xa[16][66];
  __shared__ float us[36][68];
  __shared__ double zz[16][40];
  __shared__ int se[16][4];
  __shared__ float swg[16][4];

  const int tid = threadIdx.x;
  const int tok0 = blockIdx.x * 16;

  { // load xa halves and sum
    const int tk = tid >> 4, j = tid & 15;
    const double* s0 = &xa_g[(size_t)(tok0 + tk) * 64 + j * 4];
    const double* s1 = s0 + (size_t)8192 * 64;
#pragma unroll
    for (int m = 0; m < 4; ++m) xa[tk][j * 4 + m] = s0[m] + s1[m];
  }
  if (tid < 144) {                              // stage U rows
#pragma unroll
    for (int j = 0; j < 4; ++j) {
      int f = tid * 4 + j;
      int r = f >> 4, c4 = f & 15;
      const float* U = (r < 12) ? (U1 + r * 64) : (r < 24 ? U2 + (r - 12) * 64 : U3 + (r - 24) * 64);
      *(float4*)&us[r][c4 * 4] = *(const float4*)&U[c4 * 4];
    }
  }
  __syncthreads();

#pragma unroll
  for (int rep = 0; rep < 3; ++rep) {
    int idx = tid + 256 * rep;
    if (idx < 576) {
      int tk = idx / 36, re = idx - tk * 36;
      double acc = 0;
      const double* xr = &xa[tk][0];
      const float* ur = &us[re][0];
      for (int k = 0; k < 64; ++k) acc += xr[k] * (double)ur[k];
      zz[tk][re] = acc;
    }
  }
  __syncthreads();

  if (tid < 48) {
    const int tk = tid & 15, r = tid >> 4;
    const double* z = &zz[tk][r * 12];
    double v0 = -1e300, v1 = -1e300, v2 = -1e300;
    int i0 = 0, i1 = 0, i2 = 0;
    for (int e = 0; e < 12; ++e) {
      double v = z[e];
      if (v > v0)      { v2 = v1; i2 = i1; v1 = v0; i1 = i0; v0 = v; i0 = e; }
      else if (v > v1) { v2 = v1; i2 = i1; v1 = v; i1 = e; }
      else if (v > v2) { v2 = v; i2 = e; }
    }
    const double inv_tau = 1.0 / (1.0 + 1e-8);
    double e1 = exp((v1 - v0) * inv_tau), e2 = exp((v2 - v0) * inv_tau);
    double s = 1.0 / (1.0 + e1 + e2);
    double w0 = s, w1 = e1 * s, w2 = e2 * s;
    int n = tok0 + tk;
    if (r < 2) {
      int jj3[3] = { i0, i1, i2 };
      double ww[3] = { w0, w1, w2 };
      for (int j = 0; j < 3; ++j) {
        int slot = (r * 3 + j) * 12 + jj3[j];
        int pos = atomicAdd(&cnt[slot], 1);
        ltok[slot * CAP + pos] = n;
        lwgt[slot * CAP + pos] = (float)ww[j];
      }
    } else {
      se[tk][0] = i0; se[tk][1] = i1; se[tk][2] = i2;
      swg[tk][0] = (float)w0; swg[tk][1] = (float)w1; swg[tk][2] = (float)w2;
    }
  }
  __syncthreads();

#pragma unroll
  for (int j = 0; j < 16; ++j) {
    int f = tid + 256 * j;
    int tk = f >> 8, c4 = f & 255;
    const float w0 = swg[tk][0], w1 = swg[tk][1], w2 = swg[tk][2];
    float4 a = *(const float4*)&b2[(size_t)se[tk][0] * 1024 + c4 * 4];
    float4 b = *(const float4*)&b2[(size_t)se[tk][1] * 1024 + c4 * 4];
    float4 d = *(const float4*)&b2[(size_t)se[tk][2] * 1024 + c4 * 4];
    fx4 o;
    o.x = w0 * a.x + w1 * b.x + w2 * d.x;
    o.y = w0 * a.y + w1 * b.y + w2 * d.y;
    o.z = w0 * a.z + w1 * b.z + w2 * d.z;
    o.w = w0 * a.w + w1 * b.w + w2 * d.w;
    __builtin_nontemporal_store(o, (fx4*)&out[(size_t)(tok0 + tk) * 1024 + c4 * 4]);
  }
}

// ---------------- tile descriptor build (128-row tiles) ----------------
__global__ void build_k(const int* __restrict__ cnt, int2* __restrict__ desc,
                        int* __restrict__ ntl) {
  int t = threadIdx.x;
  if (t < 6) {
    int nt = 0;
    for (int e = 0; e < 12; ++e) {
      int c = cnt[t * 12 + e];
      for (int s = 0; s < c; s += 128) { desc[t * 96 + nt] = make_int2(e, s); ++nt; }
    }
    ntl[t] = nt;
  }
}

// ---------------- grouped GEMM: fp8, 128x128, BK=64, 2-buf, 4 blocks/CU, b128 reads ----
template<int KB, int NOUT, bool ADD, typename CT>
__global__ __launch_bounds__(256, 4) void moe_gemm(
    const u8* __restrict__ A, const u8* __restrict__ W, CT* __restrict__ C,
    float outScale,
    const int* __restrict__ cnt12, const int* __restrict__ ltok12,
    const float* __restrict__ lwgt12,
    const int2* __restrict__ desc, const int* __restrict__ ntl) {
  unsigned lin = blockIdx.y * gridDim.x + blockIdx.x;
  unsigned q = (gridDim.x * gridDim.y) >> 3;
  unsigned swz = (lin & 7) * q + (lin >> 3);
  int tile = swz % gridDim.x;
  int ntile = swz / gridDim.x;
  if (tile >= *ntl) return;
  const int2 dd = desc[tile];
  const int e = dd.x, rowStart = dd.y;
  const int rows = min(128, cnt12[e] - rowStart);
  const int base = e * CAP + rowStart;

  __shared__ __align__(16) u8 As[2][8192];
  __shared__ __align__(16) u8 Bs[2][8192];
  __shared__ int tokL[128];
  __shared__ float wgtL[128];

  const int tid = threadIdx.x;
  const int lane = tid & 63, w = tid >> 6;
  if (tid < 128) {
    int li = min(tid, rows - 1);
    tokL[tid] = ltok12[base + li];
    wgtL[tid] = lwgt12[base + li];
  }
  __syncthreads();

  const int srcSwz = (((tid & 3) ^ ((tid >> 3) & 3)) * 16);
  const u8* aSrc[2]; const u8* bSrc[2];
#pragma unroll
  for (int i = 0; i < 2; ++i) {
    int r = i * 64 + (tid >> 2);
    aSrc[i] = A + (size_t)tokL[min(r, rows - 1)] * KB + srcSwz;
    bSrc[i] = W + ((size_t)e * NOUT + ntile * 128 + r) * KB + srcSwz;
  }

  f32x4 acc[4][4] = {};
  const int wr = w >> 1, wc = w & 1;
  const int roff = 16 * ((((lane >> 4) & 3)) ^ ((lane >> 1) & 3));
  constexpr int NT = KB / 64;

#define STAGE(kt_) do { int ko_ = (kt_) * 64; int b_ = (kt_) & 1;               \
    async16(aSrc[0] + ko_, &As[b_][tid * 16]);                                  \
    async16(aSrc[1] + ko_, &As[b_][(256 + tid) * 16]);                          \
    async16(bSrc[0] + ko_, &Bs[b_][tid * 16]);                                  \
    async16(bSrc[1] + ko_, &Bs[b_][(256 + tid) * 16]); } while (0)

  STAGE(0);
  __syncthreads();
  for (int kt = 0; kt < NT; ++kt) {
    if (kt + 1 < NT) STAGE(kt + 1);
    const u8* Ab = &As[kt & 1][0];
    const u8* Bb = &Bs[kt & 1][0];
    lx2 bv[4], av[4];
#pragma unroll
    for (int ni = 0; ni < 4; ++ni) {
      int rB = wc * 64 + ni * 16 + (lane & 15);
      bv[ni] = *(const lx2*)&Bb[rB * 64 + roff];
    }
#pragma unroll
    for (int mi = 0; mi < 4; ++mi) {
      int rA = wr * 64 + mi * 16 + (lane & 15);
      av[mi] = *(const lx2*)&Ab[rA * 64 + roff];
    }
#pragma unroll
    for (int mi = 0; mi < 4; ++mi)
#pragma unroll
      for (int ni = 0; ni < 4; ++ni)
        acc[mi][ni] = __builtin_amdgcn_mfma_f32_16x16x32_fp8_fp8(av[mi].x, bv[ni].x, acc[mi][ni], 0, 0, 0);
#pragma unroll
    for (int mi = 0; mi < 4; ++mi)
#pragma unroll
      for (int ni = 0; ni < 4; ++ni)
        acc[mi][ni] = __builtin_amdgcn_mfma_f32_16x16x32_fp8_fp8(av[mi].y, bv[ni].y, acc[mi][ni], 0, 0, 0);
    __syncthreads();
  }
#undef STAGE

#pragma unroll
  for (int mi = 0; mi < 4; ++mi) {
    int lr0 = wr * 64 + mi * 16 + ((lane >> 4) << 2);
#pragma unroll
    for (int rr = 0; rr < 4; ++rr) {
      int lrow = lr0 + rr;
      bool rowok = lrow < rows;
      int tok = tokL[lrow];
      float wv = wgtL[lrow] * outScale;
      if constexpr (sizeof(CT) == 2) {
        u32* cp32 = (u32*)((u16*)C + (size_t)tok * NOUT + ntile * 128 + wc * 64 + (lane & 14));
#pragma unroll
        for (int ni = 0; ni < 4; ++ni) {
          float v = acc[mi][ni][rr] * wv;
          float vo = __shfl_xor(v, 1);
          if (rowok && !(lane & 1)) {
            float lo = v, hi = vo;
            if (ADD) {
              u32 curv = __builtin_nontemporal_load(cp32 + ni * 8);
              lo += b2f((u16)(curv & 0xffffu));
              hi += b2f((u16)(curv >> 16));
            }
            __builtin_nontemporal_store((u32)f2b(lo) | ((u32)f2b(hi) << 16), cp32 + ni * 8);
          }
        }
      } else {
        if (rowok) {
          float* cp = (float*)C + (size_t)tok * NOUT + ntile * 128 + wc * 64 + (lane & 15);
#pragma unroll
          for (int ni = 0; ni < 4; ++ni) {
            float val = acc[mi][ni][rr] * wv;
            float* p = cp + ni * 16;
            float res = ADD ? (__builtin_nontemporal_load(p) + val) : val;
            __builtin_nontemporal_store(res, p);
          }
        }
      }
    }
  }
}

// ---------------- exact GELU on bf16 h -> fp8 (x256) h8, granule-interleaved ----------------
DEVI float gelu1(float v) { return 0.5f * v * (1.0f + erff(v * 0.70710678118654752f)); }
__global__ void gelu8_k(const u32* __restrict__ h, u8* __restrict__ h8, long n8) {
  long stride = (long)gridDim.x * blockDim.x;
  const ux4* hp = (const ux4*)h;
  for (long i = (long)blockIdx.x * blockDim.x + threadIdx.x; i < n8; i += stride) {
    ux4 v = __builtin_nontemporal_load(hp + i);
    u32 words[4] = { v.x, v.y, v.z, v.w };
    float gf[8];
#pragma unroll
    for (int j = 0; j < 4; ++j) {
      gf[2 * j]     = gelu1(b2f((u16)(words[j] & 0xffffu)));
      gf[2 * j + 1] = gelu1(b2f((u16)(words[j] >> 16)));
    }
    u32 lo = pack4hw(gf[0], gf[1], gf[2], gf[3], 256.f);
    u32 hi = pack4hw(gf[4], gf[5], gf[6], gf[7], 256.f);
    long b = i >> 3; int g = (int)(i & 7);
    u32* dst = (u32*)(h8 + b * 64 + 16 * (g & 3) + 8 * (g >> 2));
    dst[0] = lo; dst[1] = hi;
  }
}

extern "C" void kernel_launch(void* const* d_in, const int* in_sizes, int n_in,
                              void* d_out, int out_size, void* d_ws, size_t ws_size,
                              hipStream_t stream) {
  const float* x  = (const float*)d_in[0];
  const float* Pw = (const float*)d_in[1];
  const float* U1 = (const float*)d_in[2];
  const float* U2 = (const float*)d_in[3];
  const float* U3 = (const float*)d_in[4];
  const float* W1 = (const float*)d_in[5];
  const float* W2 = (const float*)d_in[6];
  const float* b2 = (const float*)d_in[7];
  float* out = (float*)d_out;

  char* ws = (char*)d_ws;
  size_t o = 0;
  u8*  W1b = (u8*)(ws + o); o += (size_t)12 * 4096 * 1024;   // fp8 W1 (x1024, interleaved)
  u8*  W2b = (u8*)(ws + o); o += (size_t)12 * 1024 * 4096;   // fp8 W2 (x1024, interleaved)
  u8*  xb  = (u8*)(ws + o); o += (size_t)8192 * 1024;        // fp8 x (interleaved)
  u16* h   = (u16*)(ws + o); o += (size_t)8192 * 4096 * 2;   // bf16 h accumulate
  u8*  h8  = (u8*)(ws + o); o += (size_t)8192 * 4096;        // fp8 gelu(h) (x256, interleaved)
  double* xa_g = (double*)(ws + o); o += (size_t)2 * 8192 * 64 * 8;  // f64 partials
  int* cnt = (int*)(ws + o); o += 512;
  int2* desc = (int2*)(ws + o); o += (size_t)6 * 96 * sizeof(int2);
  o = (o + 255) & ~(size_t)255;
  int* ntl = (int*)(ws + o); o += 256;
  int* ltok = (int*)(ws + o); o += (size_t)6 * 12 * CAP * 4;
  float* lwgt = (float*)(ws + o); o += (size_t)6 * 12 * CAP * 4;
  if (ws_size < o) return;

  hipMemsetAsync(cnt, 0, 512, stream);
  cvt8_k<<<4096, 256, 0, stream>>>(W1, W1b, W2, W2b, (long)12 * 4096 * 1024);
  xaddr2_k<<<dim3(1024, 2), 256, 0, stream>>>(x, Pw, xa_g, xb);
  route2_k<<<512, 256, 0, stream>>>(xa_g, U1, U2, U3, b2, cnt, ltok, lwgt, out);
  build_k<<<1, 64, 0, stream>>>(cnt, desc, ntl);

  const float s1 = 1.0f / 1024.f;            // undo W1 scale
  const float s2 = 1.0f / (1024.f * 256.f);  // undo W2 and h scales

  { // layer 1: h = sum over ranks of w * (x @ W1[e]^T)   (bf16 RMW in ws)
    dim3 g(80, 32);
    int s;
    s = 0; moe_gemm<1024, 4096, false, u16><<<g, 256, 0, stream>>>(xb, W1b, h, s1, cnt + s * 12, ltok + (size_t)s * 12 * CAP, lwgt + (size_t)s * 12 * CAP, desc + s * 96, ntl + s);
    s = 1; moe_gemm<1024, 4096, true , u16><<<g, 256, 0, stream>>>(xb, W1b, h, s1, cnt + s * 12, ltok + (size_t)s * 12 * CAP, lwgt + (size_t)s * 12 * CAP, desc + s * 96, ntl + s);
    s = 2; moe_gemm<1024, 4096, true , u16><<<g, 256, 0, stream>>>(xb, W1b, h, s1, cnt + s * 12, ltok + (size_t)s * 12 * CAP, lwgt + (size_t)s * 12 * CAP, desc + s * 96, ntl + s);
  }

  gelu8_k<<<2048, 256, 0, stream>>>((const u32*)h, h8, (long)8192 * 4096 / 8);

  { // layer 2: out += sum over ranks of w * (gelu(h) @ W2[e]^T)   (bias already in out, f32)
    dim3 g(80, 8);
    int s;
    s = 3; moe_gemm<4096, 1024, true, float><<<g, 256, 0, stream>>>(h8, W2b, out, s2, cnt + s * 12, ltok + (size_t)s * 12 * CAP, lwgt + (size_t)s * 12 * CAP, desc + s * 96, ntl + s);
    s = 4; moe_gemm<4096, 1024, true, float><<<g, 256, 0, stream>>>(h8, W2b, out, s2, cnt + s * 12, ltok + (size_t)s * 12 * CAP, lwgt + (size_t)s * 12 * CAP, desc + s * 96, ntl + s);
    s = 5; moe_gemm<4096, 1024, true, float><<<g, 256, 0, stream>>>(h8, W2b, out, s2, cnt + s * 12, ltok + (size_t)s * 12 * CAP, lwgt + (size_t)s * 12 * CAP, desc + s * 96, ntl + s);
  }
}

// Round 14
// 912.707 us; speedup vs baseline: 1.1361x; 1.1361x over previous
//
#include <hip/hip_runtime.h>
#include <math.h>

#define DEVI __device__ __forceinline__
typedef unsigned short u16;
typedef unsigned int u32;
typedef unsigned char u8;
typedef float f32x4 __attribute__((ext_vector_type(4)));
typedef float fx4 __attribute__((ext_vector_type(4)));
typedef u32 ux4 __attribute__((ext_vector_type(4)));
typedef long lx2 __attribute__((ext_vector_type(2)));

static constexpr int CAP = 8192;   // per (router,rank,expert) list capacity

DEVI u16 f2b(float f) {            // f32 -> bf16 bits, RNE
  u32 x = __builtin_bit_cast(u32, f);
  u32 r = (x + 0x7fffu + ((x >> 16) & 1u)) >> 16;
  return (u16)r;
}
DEVI float b2f(u16 u) { return __builtin_bit_cast(float, (u32)u << 16); }

DEVI u32 f2fp8(float f) {          // f32 -> OCP e4m3fn, RNE, saturating (SW fallback)
  u32 x = __builtin_bit_cast(u32, f);
  u32 s = (x >> 24) & 0x80u;
  u32 ax = x & 0x7fffffffu;
  if (ax >= 0x43e80000u) return s | 0x7eu;
  if (ax < 0x3a800000u) return s;
  if (ax < 0x3c800000u) {
    float m = __builtin_bit_cast(float, ax) * 512.0f;
    return s | (u32)rintf(m);
  }
  u32 r = ax + 0x7ffffu + ((ax >> 20) & 1u);
  return s | (((r >> 23) - 120u) << 3) | ((r >> 20) & 7u);
}

#if __has_builtin(__builtin_amdgcn_cvt_pk_fp8_f32)
DEVI u32 pack4hw(float a, float b, float c, float d, float sc) {
  u32 lo = __builtin_amdgcn_cvt_pk_fp8_f32(a * sc, b * sc, 0, false);
  return (u32)__builtin_amdgcn_cvt_pk_fp8_f32(c * sc, d * sc, lo, true);
}
#else
DEVI u32 pack4hw(float a, float b, float c, float d, float sc) {
  return f2fp8(a * sc) | (f2fp8(b * sc) << 8) | (f2fp8(c * sc) << 16) | (f2fp8(d * sc) << 24);
}
#endif

DEVI void async16(const void* g, void* l) {
  __builtin_amdgcn_global_load_lds((const __attribute__((address_space(1))) void*)g,
                                   (__attribute__((address_space(3))) void*)l, 16, 0, 0);
}

// ---------------- f32 -> fp8(x1024), granule-interleaved, coalesced ----------------
// dest layout per 64B k-block: 16B chunk c = src granules {c, c+4} (granule = 8 elems).
__global__ void cvt8_k(const float* __restrict__ s0, u8* __restrict__ d0,
                       const float* __restrict__ s1, u8* __restrict__ d1, long n) {
  long nq0 = n / 4, nq = nq0 * 2;                    // float4 count
  long stride = (long)gridDim.x * blockDim.x;
  for (long q = (long)blockIdx.x * blockDim.x + threadIdx.x; q < nq; q += stride) {
    long qi = q; const float* s = s0; u8* d = d0;
    if (qi >= nq0) { qi -= nq0; s = s1; d = d1; }
    fx4 v = __builtin_nontemporal_load((const fx4*)s + qi);
    u32 o = pack4hw(v.x, v.y, v.z, v.w, 1024.f);
    long b = qi >> 4; int s4 = (int)(qi & 15); int g = s4 >> 1;
    *(u32*)(d + b * 64 + 16 * (g & 3) + 8 * (g >> 2) + 4 * (s4 & 1)) = o;
  }
}

// ---------------- router phase 1: x_addr partials, k-split x2, 8 tok/block ----------------
__global__ __launch_bounds__(256) void xaddr2_k(
    const float* __restrict__ x, const float* __restrict__ Pw,
    double* __restrict__ xa_g, u8* __restrict__ xb) {
  __shared__ __align__(16) char sm[19584];
  float* xs  = (float*)sm;                     // [8][68]  f32
  float* pws = (float*)(sm + 2176);            // [64][68] f32

  const int tid = threadIdx.x;
  const int tok0 = blockIdx.x * 8;
  const int kbase = blockIdx.y * 512;
  const int tok = tid >> 5, dg = tid & 31;

  double a0 = 0, a1 = 0, a2 = 0, a3 = 0;

  const int rot0 = dg >> 3;
  const int rot1 = (dg >> 3) + 4;

  for (int kc = 0; kc < 8; ++kc) {
    const int k0 = kbase + kc * 64;
    if (tid < 128) {                           // stage x + emit fp8 interleaved
      int t = tid >> 4, c4 = tid & 15;
      size_t goff = (size_t)(tok0 + t) * 1024 + k0 + c4 * 4;
      fx4 v = __builtin_nontemporal_load((const fx4*)&x[goff]);
      *(fx4*)&xs[t * 68 + c4 * 4] = v;
      int g = c4 >> 1;
      int off = 16 * (g & 3) + 8 * (g >> 2) + 4 * (c4 & 1);
      u32 o8 = pack4hw(v.x, v.y, v.z, v.w, 1.0f);
      *(u32*)&xb[(size_t)(tok0 + t) * 1024 + k0 + off] = o8;
    }
#pragma unroll
    for (int j = 0; j < 4; ++j) {              // stage Pw, rotated chunk pos
      int f = tid + 256 * j;
      int pr = f >> 4, pc = f & 15;
      int pos = (pc + (pr >> 3)) & 15;
      *(float4*)&pws[pr * 68 + pos * 4] = *(const float4*)&Pw[(size_t)pr * 1024 + k0 + pc * 4];
    }
    __syncthreads();
    const float* xrow = &xs[tok * 68];
#pragma unroll
    for (int k4 = 0; k4 < 16; ++k4) {
      float4 xv = *(const float4*)&xrow[k4 * 4];
      float4 q0 = *(const float4*)&pws[dg * 68 + ((k4 + rot0) & 15) * 4];
      float4 q1 = *(const float4*)&pws[(dg + 32) * 68 + ((k4 + rot1) & 15) * 4];
      a0 += (double)xv.x * q0.x + (double)xv.y * q0.y;
      a1 += (double)xv.z * q0.z + (double)xv.w * q0.w;
      a2 += (double)xv.x * q1.x + (double)xv.y * q1.y;
      a3 += (double)xv.z * q1.z + (double)xv.w * q1.w;
    }
    __syncthreads();
  }

  size_t base = ((size_t)blockIdx.y * 8192 + (tok0 + tok)) * 64;
  xa_g[base + dg] = a0 + a1;
  xa_g[base + dg + 32] = a2 + a3;
}

// ---------------- router phase 2: z (f64), top3+softmax, lists, bias init ----------------
__global__ __launch_bounds__(256) void route2_k(
    const double* __restrict__ xa_g,
    const float* __restrict__ U1, const float* __restrict__ U2, const float* __restrict__ U3,
    const float* __restrict__ b2,
    int* __restrict__ cnt, int* __restrict__ ltok, float* __restrict__ lwgt,
    float* __restrict__ out) {
  __shared__ double xa[16][66];
  __shared__ float us[36][68];
  __shared__ double zz[16][40];
  __shared__ int se[16][4];
  __shared__ float swg[16][4];

  const int tid = threadIdx.x;
  const int tok0 = blockIdx.x * 16;

  { // load xa halves and sum
    const int tk = tid >> 4, j = tid & 15;
    const double* s0 = &xa_g[(size_t)(tok0 + tk) * 64 + j * 4];
    const double* s1 = s0 + (size_t)8192 * 64;
#pragma unroll
    for (int m = 0; m < 4; ++m) xa[tk][j * 4 + m] = s0[m] + s1[m];
  }
  if (tid < 144) {                              // stage U rows
#pragma unroll
    for (int j = 0; j < 4; ++j) {
      int f = tid * 4 + j;
      int r = f >> 4, c4 = f & 15;
      const float* U = (r < 12) ? (U1 + r * 64) : (r < 24 ? U2 + (r - 12) * 64 : U3 + (r - 24) * 64);
      *(float4*)&us[r][c4 * 4] = *(const float4*)&U[c4 * 4];
    }
  }
  __syncthreads();

#pragma unroll
  for (int rep = 0; rep < 3; ++rep) {
    int idx = tid + 256 * rep;
    if (idx < 576) {
      int tk = idx / 36, re = idx - tk * 36;
      double acc = 0;
      const double* xr = &xa[tk][0];
      const float* ur = &us[re][0];
      for (int k = 0; k < 64; ++k) acc += xr[k] * (double)ur[k];
      zz[tk][re] = acc;
    }
  }
  __syncthreads();

  if (tid < 48) {
    const int tk = tid & 15, r = tid >> 4;
    const double* z = &zz[tk][r * 12];
    double v0 = -1e300, v1 = -1e300, v2 = -1e300;
    int i0 = 0, i1 = 0, i2 = 0;
    for (int e = 0; e < 12; ++e) {
      double v = z[e];
      if (v > v0)      { v2 = v1; i2 = i1; v1 = v0; i1 = i0; v0 = v; i0 = e; }
      else if (v > v1) { v2 = v1; i2 = i1; v1 = v; i1 = e; }
      else if (v > v2) { v2 = v; i2 = e; }
    }
    const double inv_tau = 1.0 / (1.0 + 1e-8);
    double e1 = exp((v1 - v0) * inv_tau), e2 = exp((v2 - v0) * inv_tau);
    double s = 1.0 / (1.0 + e1 + e2);
    double w0 = s, w1 = e1 * s, w2 = e2 * s;
    int n = tok0 + tk;
    if (r < 2) {
      int jj3[3] = { i0, i1, i2 };
      double ww[3] = { w0, w1, w2 };
      for (int j = 0; j < 3; ++j) {
        int slot = (r * 3 + j) * 12 + jj3[j];
        int pos = atomicAdd(&cnt[slot], 1);
        ltok[slot * CAP + pos] = n;
        lwgt[slot * CAP + pos] = (float)ww[j];
      }
    } else {
      se[tk][0] = i0; se[tk][1] = i1; se[tk][2] = i2;
      swg[tk][0] = (float)w0; swg[tk][1] = (float)w1; swg[tk][2] = (float)w2;
    }
  }
  __syncthreads();

#pragma unroll
  for (int j = 0; j < 16; ++j) {
    int f = tid + 256 * j;
    int tk = f >> 8, c4 = f & 255;
    const float w0 = swg[tk][0], w1 = swg[tk][1], w2 = swg[tk][2];
    float4 a = *(const float4*)&b2[(size_t)se[tk][0] * 1024 + c4 * 4];
    float4 b = *(const float4*)&b2[(size_t)se[tk][1] * 1024 + c4 * 4];
    float4 d = *(const float4*)&b2[(size_t)se[tk][2] * 1024 + c4 * 4];
    float4 o;
    o.x = w0 * a.x + w1 * b.x + w2 * d.x;
    o.y = w0 * a.y + w1 * b.y + w2 * d.y;
    o.z = w0 * a.z + w1 * b.z + w2 * d.z;
    o.w = w0 * a.w + w1 * b.w + w2 * d.w;
    *(float4*)&out[(size_t)(tok0 + tk) * 1024 + c4 * 4] = o;
  }
}

// ---------------- tile descriptor build (128-row tiles) ----------------
__global__ void build_k(const int* __restrict__ cnt, int2* __restrict__ desc,
                        int* __restrict__ ntl) {
  int t = threadIdx.x;
  if (t < 6) {
    int nt = 0;
    for (int e = 0; e < 12; ++e) {
      int c = cnt[t * 12 + e];
      for (int s = 0; s < c; s += 128) { desc[t * 96 + nt] = make_int2(e, s); ++nt; }
    }
    ntl[t] = nt;
  }
}

// ---------------- grouped GEMM: fp8, 128x128, BK=64, 2-buf, 32KB LDS, b128 reads ----
template<int KB, int NOUT, bool ADD, typename CT>
__global__ __launch_bounds__(256, 4) void moe_gemm(
    const u8* __restrict__ A, const u8* __restrict__ W, CT* __restrict__ C,
    float outScale,
    const int* __restrict__ cnt12, const int* __restrict__ ltok12,
    const float* __restrict__ lwgt12,
    const int2* __restrict__ desc, const int* __restrict__ ntl) {
  unsigned lin = blockIdx.y * gridDim.x + blockIdx.x;
  unsigned q = (gridDim.x * gridDim.y) >> 3;
  unsigned swz = (lin & 7) * q + (lin >> 3);
  int tile = swz % gridDim.x;
  int ntile = swz / gridDim.x;
  if (tile >= *ntl) return;
  const int2 dd = desc[tile];
  const int e = dd.x, rowStart = dd.y;
  const int rows = min(128, cnt12[e] - rowStart);
  const int base = e * CAP + rowStart;

  __shared__ __align__(16) u8 As[2][8192];     // exactly 32 KB total
  __shared__ __align__(16) u8 Bs[2][8192];

  const int tid = threadIdx.x;
  const int lane = tid & 63, w = tid >> 6;

  const int srcSwz = (((tid & 3) ^ ((tid >> 3) & 3)) * 16);
  const u8* aSrc[2]; const u8* bSrc[2];
#pragma unroll
  for (int i = 0; i < 2; ++i) {
    int r = i * 64 + (tid >> 2);
    aSrc[i] = A + (size_t)ltok12[base + min(r, rows - 1)] * KB + srcSwz;
    bSrc[i] = W + ((size_t)e * NOUT + ntile * 128 + r) * KB + srcSwz;
  }

  f32x4 acc[4][4] = {};
  const int wr = w >> 1, wc = w & 1;
  const int roff = 16 * ((((lane >> 4) & 3)) ^ ((lane >> 1) & 3));
  constexpr int NT = KB / 64;

#define STAGE(kt_) do { int ko_ = (kt_) * 64; int b_ = (kt_) & 1;               \
    async16(aSrc[0] + ko_, &As[b_][tid * 16]);                                  \
    async16(aSrc[1] + ko_, &As[b_][(256 + tid) * 16]);                          \
    async16(bSrc[0] + ko_, &Bs[b_][tid * 16]);                                  \
    async16(bSrc[1] + ko_, &Bs[b_][(256 + tid) * 16]); } while (0)

  STAGE(0);
  __syncthreads();
  for (int kt = 0; kt < NT; ++kt) {
    if (kt + 1 < NT) STAGE(kt + 1);
    const u8* Ab = &As[kt & 1][0];
    const u8* Bb = &Bs[kt & 1][0];
    lx2 bv[4], av[4];
#pragma unroll
    for (int ni = 0; ni < 4; ++ni) {
      int rB = wc * 64 + ni * 16 + (lane & 15);
      bv[ni] = *(const lx2*)&Bb[rB * 64 + roff];
    }
#pragma unroll
    for (int mi = 0; mi < 4; ++mi) {
      int rA = wr * 64 + mi * 16 + (lane & 15);
      av[mi] = *(const lx2*)&Ab[rA * 64 + roff];
    }
#pragma unroll
    for (int mi = 0; mi < 4; ++mi)
#pragma unroll
      for (int ni = 0; ni < 4; ++ni)
        acc[mi][ni] = __builtin_amdgcn_mfma_f32_16x16x32_fp8_fp8(av[mi].x, bv[ni].x, acc[mi][ni], 0, 0, 0);
#pragma unroll
    for (int mi = 0; mi < 4; ++mi)
#pragma unroll
      for (int ni = 0; ni < 4; ++ni)
        acc[mi][ni] = __builtin_amdgcn_mfma_f32_16x16x32_fp8_fp8(av[mi].y, bv[ni].y, acc[mi][ni], 0, 0, 0);
    __syncthreads();
  }
#undef STAGE

#pragma unroll
  for (int mi = 0; mi < 4; ++mi) {
    int lr0 = wr * 64 + mi * 16 + ((lane >> 4) << 2);
#pragma unroll
    for (int rr = 0; rr < 4; ++rr) {
      int lrow = lr0 + rr;
      bool rowok = lrow < rows;
      int idx = base + (rowok ? lrow : 0);
      int tok = ltok12[idx];
      float wv = lwgt12[idx] * outScale;
      if constexpr (sizeof(CT) == 2) {
        u32* cp32 = (u32*)((u16*)C + (size_t)tok * NOUT + ntile * 128 + wc * 64 + (lane & 14));
#pragma unroll
        for (int ni = 0; ni < 4; ++ni) {
          float v = acc[mi][ni][rr] * wv;
          float vo = __shfl_xor(v, 1);
          if (rowok && !(lane & 1)) {
            float lo = v, hi = vo;
            if (ADD) {
              u32 curv = cp32[ni * 8];
              lo += b2f((u16)(curv & 0xffffu));
              hi += b2f((u16)(curv >> 16));
            }
            cp32[ni * 8] = (u32)f2b(lo) | ((u32)f2b(hi) << 16);
          }
        }
      } else {
        if (rowok) {
          float* cp = (float*)C + (size_t)tok * NOUT + ntile * 128 + wc * 64 + (lane & 15);
#pragma unroll
          for (int ni = 0; ni < 4; ++ni) {
            float val = acc[mi][ni][rr] * wv;
            float* p = cp + ni * 16;
            *p = ADD ? (*p + val) : val;
          }
        }
      }
    }
  }
}

// ---------------- exact GELU on bf16 h -> fp8 (x256) h8, granule-interleaved ----------------
DEVI float gelu1(float v) { return 0.5f * v * (1.0f + erff(v * 0.70710678118654752f)); }
__global__ void gelu8_k(const u32* __restrict__ h, u8* __restrict__ h8, long n8) {
  long stride = (long)gridDim.x * blockDim.x;
  const ux4* hp = (const ux4*)h;
  for (long i = (long)blockIdx.x * blockDim.x + threadIdx.x; i < n8; i += stride) {
    ux4 v = __builtin_nontemporal_load(hp + i);
    u32 words[4] = { v.x, v.y, v.z, v.w };
    float gf[8];
#pragma unroll
    for (int j = 0; j < 4; ++j) {
      gf[2 * j]     = gelu1(b2f((u16)(words[j] & 0xffffu)));
      gf[2 * j + 1] = gelu1(b2f((u16)(words[j] >> 16)));
    }
    u32 lo = pack4hw(gf[0], gf[1], gf[2], gf[3], 256.f);
    u32 hi = pack4hw(gf[4], gf[5], gf[6], gf[7], 256.f);
    long b = i >> 3; int g = (int)(i & 7);
    u32* dst = (u32*)(h8 + b * 64 + 16 * (g & 3) + 8 * (g >> 2));
    dst[0] = lo; dst[1] = hi;
  }
}

extern "C" void kernel_launch(void* const* d_in, const int* in_sizes, int n_in,
                              void* d_out, int out_size, void* d_ws, size_t ws_size,
                              hipStream_t stream) {
  const float* x  = (const float*)d_in[0];
  const float* Pw = (const float*)d_in[1];
  const float* U1 = (const float*)d_in[2];
  const float* U2 = (const float*)d_in[3];
  const float* U3 = (const float*)d_in[4];
  const float* W1 = (const float*)d_in[5];
  const float* W2 = (const float*)d_in[6];
  const float* b2 = (const float*)d_in[7];
  float* out = (float*)d_out;

  char* ws = (char*)d_ws;
  size_t o = 0;
  u8*  W1b = (u8*)(ws + o); o += (size_t)12 * 4096 * 1024;   // fp8 W1 (x1024, interleaved)
  u8*  W2b = (u8*)(ws + o); o += (size_t)12 * 1024 * 4096;   // fp8 W2 (x1024, interleaved)
  u8*  xb  = (u8*)(ws + o); o += (size_t)8192 * 1024;        // fp8 x (interleaved)
  u16* h   = (u16*)(ws + o); o += (size_t)8192 * 4096 * 2;   // bf16 h accumulate
  u8*  h8  = (u8*)(ws + o); o += (size_t)8192 * 4096;        // fp8 gelu(h) (x256, interleaved)
  double* xa_g = (double*)(ws + o); o += (size_t)2 * 8192 * 64 * 8;  // f64 partials
  int* cnt = (int*)(ws + o); o += 512;
  int2* desc = (int2*)(ws + o); o += (size_t)6 * 96 * sizeof(int2);
  o = (o + 255) & ~(size_t)255;
  int* ntl = (int*)(ws + o); o += 256;
  int* ltok = (int*)(ws + o); o += (size_t)6 * 12 * CAP * 4;
  float* lwgt = (float*)(ws + o); o += (size_t)6 * 12 * CAP * 4;
  if (ws_size < o) return;

  hipMemsetAsync(cnt, 0, 512, stream);
  cvt8_k<<<4096, 256, 0, stream>>>(W1, W1b, W2, W2b, (long)12 * 4096 * 1024);
  xaddr2_k<<<dim3(1024, 2), 256, 0, stream>>>(x, Pw, xa_g, xb);
  route2_k<<<512, 256, 0, stream>>>(xa_g, U1, U2, U3, b2, cnt, ltok, lwgt, out);
  build_k<<<1, 64, 0, stream>>>(cnt, desc, ntl);

  const float s1 = 1.0f / 1024.f;            // undo W1 scale
  const float s2 = 1.0f / (1024.f * 256.f);  // undo W2 and h scales

  { // layer 1: h = sum over ranks of w * (x @ W1[e]^T)   (bf16 RMW in ws)
    dim3 g(80, 32);
    int s;
    s = 0; moe_gemm<1024, 4096, false, u16><<<g, 256, 0, stream>>>(xb, W1b, h, s1, cnt + s * 12, ltok + (size_t)s * 12 * CAP, lwgt + (size_t)s * 12 * CAP, desc + s * 96, ntl + s);
    s = 1; moe_gemm<1024, 4096, true , u16><<<g, 256, 0, stream>>>(xb, W1b, h, s1, cnt + s * 12, ltok + (size_t)s * 12 * CAP, lwgt + (size_t)s * 12 * CAP, desc + s * 96, ntl + s);
    s = 2; moe_gemm<1024, 4096, true , u16><<<g, 256, 0, stream>>>(xb, W1b, h, s1, cnt + s * 12, ltok + (size_t)s * 12 * CAP, lwgt + (size_t)s * 12 * CAP, desc + s * 96, ntl + s);
  }

  gelu8_k<<<2048, 256, 0, stream>>>((const u32*)h, h8, (long)8192 * 4096 / 8);

  { // layer 2: out += sum over ranks of w * (gelu(h) @ W2[e]^T)   (bias already in out, f32)
    dim3 g(80, 8);
    int s;
    s = 3; moe_gemm<4096, 1024, true, float><<<g, 256, 0, stream>>>(h8, W2b, out, s2, cnt + s * 12, ltok + (size_t)s * 12 * CAP, lwgt + (size_t)s * 12 * CAP, desc + s * 96, ntl + s);
    s = 4; moe_gemm<4096, 1024, true, float><<<g, 256, 0, stream>>>(h8, W2b, out, s2, cnt + s * 12, ltok + (size_t)s * 12 * CAP, lwgt + (size_t)s * 12 * CAP, desc + s * 96, ntl + s);
    s = 5; moe_gemm<4096, 1024, true, float><<<g, 256, 0, stream>>>(h8, W2b, out, s2, cnt + s * 12, ltok + (size_t)s * 12 * CAP, lwgt + (size_t)s * 12 * CAP, desc + s * 96, ntl + s);
  }
}

// Round 15
// 884.485 us; speedup vs baseline: 1.1724x; 1.0319x over previous
//
#include <hip/hip_runtime.h>
#include <math.h>

#define DEVI __device__ __forceinline__
typedef unsigned short u16;
typedef unsigned int u32;
typedef unsigned char u8;
typedef float f32x4 __attribute__((ext_vector_type(4)));
typedef float fx4 __attribute__((ext_vector_type(4)));
typedef u32 ux4 __attribute__((ext_vector_type(4)));

static constexpr int CAP = 8192;   // per (router,rank,expert) list capacity

DEVI u16 f2b(float f) {            // f32 -> bf16 bits, RNE
  u32 x = __builtin_bit_cast(u32, f);
  u32 r = (x + 0x7fffu + ((x >> 16) & 1u)) >> 16;
  return (u16)r;
}
DEVI float b2f(u16 u) { return __builtin_bit_cast(float, (u32)u << 16); }

DEVI u32 f2fp8(float f) {          // f32 -> OCP e4m3fn, RNE, saturating (SW fallback)
  u32 x = __builtin_bit_cast(u32, f);
  u32 s = (x >> 24) & 0x80u;
  u32 ax = x & 0x7fffffffu;
  if (ax >= 0x43e80000u) return s | 0x7eu;
  if (ax < 0x3a800000u) return s;
  if (ax < 0x3c800000u) {
    float m = __builtin_bit_cast(float, ax) * 512.0f;
    return s | (u32)rintf(m);
  }
  u32 r = ax + 0x7ffffu + ((ax >> 20) & 1u);
  return s | (((r >> 23) - 120u) << 3) | ((r >> 20) & 7u);
}

#if __has_builtin(__builtin_amdgcn_cvt_pk_fp8_f32)
DEVI u32 pack4hw(float a, float b, float c, float d, float sc) {
  u32 lo = __builtin_amdgcn_cvt_pk_fp8_f32(a * sc, b * sc, 0, false);
  return (u32)__builtin_amdgcn_cvt_pk_fp8_f32(c * sc, d * sc, lo, true);
}
DEVI u32 pack2hw(float a, float b, float sc) {
  return __builtin_amdgcn_cvt_pk_fp8_f32(a * sc, b * sc, 0, false) & 0xffffu;
}
#else
DEVI u32 pack4hw(float a, float b, float c, float d, float sc) {
  return f2fp8(a * sc) | (f2fp8(b * sc) << 8) | (f2fp8(c * sc) << 16) | (f2fp8(d * sc) << 24);
}
DEVI u32 pack2hw(float a, float b, float sc) {
  return f2fp8(a * sc) | (f2fp8(b * sc) << 8);
}
#endif

DEVI void async16(const void* g, void* l) {
  __builtin_amdgcn_global_load_lds((const __attribute__((address_space(1))) void*)g,
                                   (__attribute__((address_space(3))) void*)l, 16, 0, 0);
}

DEVI float gelu1(float v) { return 0.5f * v * (1.0f + erff(v * 0.70710678118654752f)); }

// ---------------- f32 -> fp8(x1024), linear, coalesced ----------------
__global__ void cvt8_k(const float* __restrict__ s0, u8* __restrict__ d0,
                       const float* __restrict__ s1, u8* __restrict__ d1, long n) {
  long nq0 = n / 4, nq = nq0 * 2;                    // float4 count
  long stride = (long)gridDim.x * blockDim.x;
  for (long q = (long)blockIdx.x * blockDim.x + threadIdx.x; q < nq; q += stride) {
    long qi = q; const float* s = s0; u8* d = d0;
    if (qi >= nq0) { qi -= nq0; s = s1; d = d1; }
    fx4 v = __builtin_nontemporal_load((const fx4*)s + qi);
    ((u32*)d)[qi] = pack4hw(v.x, v.y, v.z, v.w, 1024.f);
  }
}

// ---------------- router phase 1: x_addr partials, k-split x2, 8 tok/block ----------------
__global__ __launch_bounds__(256) void xaddr2_k(
    const float* __restrict__ x, const float* __restrict__ Pw,
    double* __restrict__ xa_g, u8* __restrict__ xb) {
  __shared__ __align__(16) char sm[19584];
  float* xs  = (float*)sm;                     // [8][68]  f32
  float* pws = (float*)(sm + 2176);            // [64][68] f32

  const int tid = threadIdx.x;
  const int tok0 = blockIdx.x * 8;
  const int kbase = blockIdx.y * 512;
  const int tok = tid >> 5, dg = tid & 31;

  double a0 = 0, a1 = 0, a2 = 0, a3 = 0;

  const int rot0 = dg >> 3;
  const int rot1 = (dg >> 3) + 4;

  for (int kc = 0; kc < 8; ++kc) {
    const int k0 = kbase + kc * 64;
    if (tid < 128) {                           // stage x + emit fp8 (linear)
      int t = tid >> 4, c4 = tid & 15;
      size_t goff = (size_t)(tok0 + t) * 1024 + k0 + c4 * 4;
      fx4 v = __builtin_nontemporal_load((const fx4*)&x[goff]);
      *(fx4*)&xs[t * 68 + c4 * 4] = v;
      *(u32*)&xb[goff] = pack4hw(v.x, v.y, v.z, v.w, 1.0f);
    }
#pragma unroll
    for (int j = 0; j < 4; ++j) {              // stage Pw, rotated chunk pos
      int f = tid + 256 * j;
      int pr = f >> 4, pc = f & 15;
      int pos = (pc + (pr >> 3)) & 15;
      *(float4*)&pws[pr * 68 + pos * 4] = *(const float4*)&Pw[(size_t)pr * 1024 + k0 + pc * 4];
    }
    __syncthreads();
    const float* xrow = &xs[tok * 68];
#pragma unroll
    for (int k4 = 0; k4 < 16; ++k4) {
      float4 xv = *(const float4*)&xrow[k4 * 4];
      float4 q0 = *(const float4*)&pws[dg * 68 + ((k4 + rot0) & 15) * 4];
      float4 q1 = *(const float4*)&pws[(dg + 32) * 68 + ((k4 + rot1) & 15) * 4];
      a0 += (double)xv.x * q0.x + (double)xv.y * q0.y;
      a1 += (double)xv.z * q0.z + (double)xv.w * q0.w;
      a2 += (double)xv.x * q1.x + (double)xv.y * q1.y;
      a3 += (double)xv.z * q1.z + (double)xv.w * q1.w;
    }
    __syncthreads();
  }

  size_t base = ((size_t)blockIdx.y * 8192 + (tok0 + tok)) * 64;
  xa_g[base + dg] = a0 + a1;
  xa_g[base + dg + 32] = a2 + a3;
}

// ---------------- router phase 2: z (f64), top3+softmax, lists, bias init ----------------
__global__ __launch_bounds__(256) void route2_k(
    const double* __restrict__ xa_g,
    const float* __restrict__ U1, const float* __restrict__ U2, const float* __restrict__ U3,
    const float* __restrict__ b2,
    int* __restrict__ cnt, int* __restrict__ ltok, float* __restrict__ lwgt,
    float* __restrict__ out) {
  __shared__ double xa[16][66];
  __shared__ float us[36][68];
  __shared__ double zz[16][40];
  __shared__ int se[16][4];
  __shared__ float swg[16][4];

  const int tid = threadIdx.x;
  const int tok0 = blockIdx.x * 16;

  { // load xa halves and sum
    const int tk = tid >> 4, j = tid & 15;
    const double* s0 = &xa_g[(size_t)(tok0 + tk) * 64 + j * 4];
    const double* s1 = s0 + (size_t)8192 * 64;
#pragma unroll
    for (int m = 0; m < 4; ++m) xa[tk][j * 4 + m] = s0[m] + s1[m];
  }
  if (tid < 144) {                              // stage U rows
#pragma unroll
    for (int j = 0; j < 4; ++j) {
      int f = tid * 4 + j;
      int r = f >> 4, c4 = f & 15;
      const float* U = (r < 12) ? (U1 + r * 64) : (r < 24 ? U2 + (r - 12) * 64 : U3 + (r - 24) * 64);
      *(float4*)&us[r][c4 * 4] = *(const float4*)&U[c4 * 4];
    }
  }
  __syncthreads();

#pragma unroll
  for (int rep = 0; rep < 3; ++rep) {
    int idx = tid + 256 * rep;
    if (idx < 576) {
      int tk = idx / 36, re = idx - tk * 36;
      double acc = 0;
      const double* xr = &xa[tk][0];
      const float* ur = &us[re][0];
      for (int k = 0; k < 64; ++k) acc += xr[k] * (double)ur[k];
      zz[tk][re] = acc;
    }
  }
  __syncthreads();

  if (tid < 48) {
    const int tk = tid & 15, r = tid >> 4;
    const double* z = &zz[tk][r * 12];
    double v0 = -1e300, v1 = -1e300, v2 = -1e300;
    int i0 = 0, i1 = 0, i2 = 0;
    for (int e = 0; e < 12; ++e) {
      double v = z[e];
      if (v > v0)      { v2 = v1; i2 = i1; v1 = v0; i1 = i0; v0 = v; i0 = e; }
      else if (v > v1) { v2 = v1; i2 = i1; v1 = v; i1 = e; }
      else if (v > v2) { v2 = v; i2 = e; }
    }
    const double inv_tau = 1.0 / (1.0 + 1e-8);
    double e1 = exp((v1 - v0) * inv_tau), e2 = exp((v2 - v0) * inv_tau);
    double s = 1.0 / (1.0 + e1 + e2);
    double w0 = s, w1 = e1 * s, w2 = e2 * s;
    int n = tok0 + tk;
    if (r < 2) {
      int jj3[3] = { i0, i1, i2 };
      double ww[3] = { w0, w1, w2 };
      for (int j = 0; j < 3; ++j) {
        int slot = (r * 3 + j) * 12 + jj3[j];
        int pos = atomicAdd(&cnt[slot], 1);
        ltok[slot * CAP + pos] = n;
        lwgt[slot * CAP + pos] = (float)ww[j];
      }
    } else {
      se[tk][0] = i0; se[tk][1] = i1; se[tk][2] = i2;
      swg[tk][0] = (float)w0; swg[tk][1] = (float)w1; swg[tk][2] = (float)w2;
    }
  }
  __syncthreads();

#pragma unroll
  for (int j = 0; j < 16; ++j) {
    int f = tid + 256 * j;
    int tk = f >> 8, c4 = f & 255;
    const float w0 = swg[tk][0], w1 = swg[tk][1], w2 = swg[tk][2];
    float4 a = *(const float4*)&b2[(size_t)se[tk][0] * 1024 + c4 * 4];
    float4 b = *(const float4*)&b2[(size_t)se[tk][1] * 1024 + c4 * 4];
    float4 d = *(const float4*)&b2[(size_t)se[tk][2] * 1024 + c4 * 4];
    float4 o;
    o.x = w0 * a.x + w1 * b.x + w2 * d.x;
    o.y = w0 * a.y + w1 * b.y + w2 * d.y;
    o.z = w0 * a.z + w1 * b.z + w2 * d.z;
    o.w = w0 * a.w + w1 * b.w + w2 * d.w;
    *(float4*)&out[(size_t)(tok0 + tk) * 1024 + c4 * 4] = o;
  }
}

// ---------------- tile descriptor build (128-row tiles) ----------------
__global__ void build_k(const int* __restrict__ cnt, int2* __restrict__ desc,
                        int* __restrict__ ntl) {
  int t = threadIdx.x;
  if (t < 6) {
    int nt = 0;
    for (int e = 0; e < 12; ++e) {
      int c = cnt[t * 12 + e];
      for (int s = 0; s < c; s += 128) { desc[t * 96 + nt] = make_int2(e, s); ++nt; }
    }
    ntl[t] = nt;
  }
}

// ---------------- grouped GEMM: fp8, 128x128, BK=64, 2-buf, 4 blocks/CU (r7 core) ----
// CT=u16: bf16 RMW into h; GELU=true (final rank): write fp8(gelu(h_final)*256) to h8o.
// CT=float: f32 RMW into out.
template<int KB, int NOUT, bool ADD, bool GELU, typename CT>
__global__ __launch_bounds__(256, 4) void moe_gemm(
    const u8* __restrict__ A, const u8* __restrict__ W, CT* __restrict__ C,
    u8* __restrict__ h8o, float outScale,
    const int* __restrict__ cnt12, const int* __restrict__ ltok12,
    const float* __restrict__ lwgt12,
    const int2* __restrict__ desc, const int* __restrict__ ntl) {
  unsigned lin = blockIdx.y * gridDim.x + blockIdx.x;
  unsigned q = (gridDim.x * gridDim.y) >> 3;
  unsigned swz = (lin & 7) * q + (lin >> 3);
  int tile = swz % gridDim.x;
  int ntile = swz / gridDim.x;
  if (tile >= *ntl) return;
  const int2 dd = desc[tile];
  const int e = dd.x, rowStart = dd.y;
  const int rows = min(128, cnt12[e] - rowStart);
  const int base = e * CAP + rowStart;

  __shared__ __align__(16) u8 As[2][8192];
  __shared__ __align__(16) u8 Bs[2][8192];
  __shared__ int tokL[128];
  __shared__ float wgtL[128];

  const int tid = threadIdx.x;
  const int lane = tid & 63, w = tid >> 6;
  if (tid < 128) {
    int li = min(tid, rows - 1);
    tokL[tid] = ltok12[base + li];
    wgtL[tid] = lwgt12[base + li];
  }
  __syncthreads();

  const int srcSwz = (((tid & 3) ^ ((tid >> 3) & 3)) * 16);
  const u8* aSrc[2]; const u8* bSrc[2];
#pragma unroll
  for (int i = 0; i < 2; ++i) {
    int r = i * 64 + (tid >> 2);
    aSrc[i] = A + (size_t)tokL[min(r, rows - 1)] * KB + srcSwz;
    bSrc[i] = W + ((size_t)e * NOUT + ntile * 128 + r) * KB + srcSwz;
  }

  f32x4 acc[4][4] = {};
  const int wr = w >> 1, wc = w & 1;
  const int sxr = (lane >> 1) & 3;
  const int p8 = ((lane >> 4) & 1) * 8;
  const int roff0 = 16 * (((lane >> 5) | 0) ^ sxr) + p8;
  const int roff1 = 16 * (((lane >> 5) | 2) ^ sxr) + p8;
  constexpr int NT = KB / 64;

#define STAGE(kt_) do { int ko_ = (kt_) * 64; int b_ = (kt_) & 1;               \
    async16(aSrc[0] + ko_, &As[b_][tid * 16]);                                  \
    async16(aSrc[1] + ko_, &As[b_][(256 + tid) * 16]);                          \
    async16(bSrc[0] + ko_, &Bs[b_][tid * 16]);                                  \
    async16(bSrc[1] + ko_, &Bs[b_][(256 + tid) * 16]); } while (0)

  STAGE(0);
  __syncthreads();
  for (int kt = 0; kt < NT; ++kt) {
    if (kt + 1 < NT) STAGE(kt + 1);
    const u8* Ab = &As[kt & 1][0];
    const u8* Bb = &Bs[kt & 1][0];
#pragma unroll
    for (int kk = 0; kk < 2; ++kk) {
      const int ro = kk ? roff1 : roff0;
      long bf[4];
#pragma unroll
      for (int ni = 0; ni < 4; ++ni) {
        int rB = wc * 64 + ni * 16 + (lane & 15);
        bf[ni] = *(const long*)&Bb[rB * 64 + ro];
      }
#pragma unroll
      for (int mi = 0; mi < 4; ++mi) {
        int rA = wr * 64 + mi * 16 + (lane & 15);
        long af = *(const long*)&Ab[rA * 64 + ro];
#pragma unroll
        for (int ni = 0; ni < 4; ++ni)
          acc[mi][ni] = __builtin_amdgcn_mfma_f32_16x16x32_fp8_fp8(af, bf[ni], acc[mi][ni], 0, 0, 0);
      }
    }
    __syncthreads();
  }
#undef STAGE

#pragma unroll
  for (int mi = 0; mi < 4; ++mi) {
    int lr0 = wr * 64 + mi * 16 + ((lane >> 4) << 2);
#pragma unroll
    for (int rr = 0; rr < 4; ++rr) {
      int lrow = lr0 + rr;
      bool rowok = lrow < rows;
      int tok = tokL[lrow];
      float wv = wgtL[lrow] * outScale;
      if constexpr (sizeof(CT) == 2) {
        size_t celt = (size_t)tok * NOUT + ntile * 128 + wc * 64 + (lane & 14);
        u32* cp32 = (u32*)((u16*)C + celt);
#pragma unroll
        for (int ni = 0; ni < 4; ++ni) {
          float v = acc[mi][ni][rr] * wv;
          float vo = __shfl_xor(v, 1);
          if (rowok && !(lane & 1)) {
            float lo = v, hi = vo;
            if (ADD) {
              u32 curv = cp32[ni * 8];
              lo += b2f((u16)(curv & 0xffffu));
              hi += b2f((u16)(curv >> 16));
            }
            if constexpr (GELU) {
              *(u16*)(h8o + celt + ni * 16) =
                  (u16)pack2hw(gelu1(lo), gelu1(hi), 256.f);
            } else {
              cp32[ni * 8] = (u32)f2b(lo) | ((u32)f2b(hi) << 16);
            }
          }
        }
      } else {
        if (rowok) {
          float* cp = (float*)C + (size_t)tok * NOUT + ntile * 128 + wc * 64 + (lane & 15);
#pragma unroll
          for (int ni = 0; ni < 4; ++ni) {
            float val = acc[mi][ni][rr] * wv;
            float* p = cp + ni * 16;
            *p = ADD ? (*p + val) : val;
          }
        }
      }
    }
  }
}

extern "C" void kernel_launch(void* const* d_in, const int* in_sizes, int n_in,
                              void* d_out, int out_size, void* d_ws, size_t ws_size,
                              hipStream_t stream) {
  const float* x  = (const float*)d_in[0];
  const float* Pw = (const float*)d_in[1];
  const float* U1 = (const float*)d_in[2];
  const float* U2 = (const float*)d_in[3];
  const float* U3 = (const float*)d_in[4];
  const float* W1 = (const float*)d_in[5];
  const float* W2 = (const float*)d_in[6];
  const float* b2 = (const float*)d_in[7];
  float* out = (float*)d_out;

  char* ws = (char*)d_ws;
  size_t o = 0;
  u8*  W1b = (u8*)(ws + o); o += (size_t)12 * 4096 * 1024;   // fp8 W1 (x1024)
  u8*  W2b = (u8*)(ws + o); o += (size_t)12 * 1024 * 4096;   // fp8 W2 (x1024)
  u8*  xb  = (u8*)(ws + o); o += (size_t)8192 * 1024;        // fp8 x
  u16* h   = (u16*)(ws + o); o += (size_t)8192 * 4096 * 2;   // bf16 h (ranks 0,1)
  u8*  h8  = (u8*)(ws + o); o += (size_t)8192 * 4096;        // fp8 gelu(h) (x256)
  double* xa_g = (double*)(ws + o); o += (size_t)2 * 8192 * 64 * 8;  // f64 partials
  int* cnt = (int*)(ws + o); o += 512;
  int2* desc = (int2*)(ws + o); o += (size_t)6 * 96 * sizeof(int2);
  o = (o + 255) & ~(size_t)255;
  int* ntl = (int*)(ws + o); o += 256;
  int* ltok = (int*)(ws + o); o += (size_t)6 * 12 * CAP * 4;
  float* lwgt = (float*)(ws + o); o += (size_t)6 * 12 * CAP * 4;
  if (ws_size < o) return;

  hipMemsetAsync(cnt, 0, 512, stream);
  cvt8_k<<<4096, 256, 0, stream>>>(W1, W1b, W2, W2b, (long)12 * 4096 * 1024);
  xaddr2_k<<<dim3(1024, 2), 256, 0, stream>>>(x, Pw, xa_g, xb);
  route2_k<<<512, 256, 0, stream>>>(xa_g, U1, U2, U3, b2, cnt, ltok, lwgt, out);
  build_k<<<1, 64, 0, stream>>>(cnt, desc, ntl);

  const float s1 = 1.0f / 1024.f;            // undo W1 scale
  const float s2 = 1.0f / (1024.f * 256.f);  // undo W2 and h scales

  { // layer 1: h = sum over ranks of w * (x @ W1[e]^T); final rank writes gelu -> h8
    dim3 g(80, 32);
    int s;
    s = 0; moe_gemm<1024, 4096, false, false, u16><<<g, 256, 0, stream>>>(xb, W1b, h, h8, s1, cnt + s * 12, ltok + (size_t)s * 12 * CAP, lwgt + (size_t)s * 12 * CAP, desc + s * 96, ntl + s);
    s = 1; moe_gemm<1024, 4096, true , false, u16><<<g, 256, 0, stream>>>(xb, W1b, h, h8, s1, cnt + s * 12, ltok + (size_t)s * 12 * CAP, lwgt + (size_t)s * 12 * CAP, desc + s * 96, ntl + s);
    s = 2; moe_gemm<1024, 4096, true , true , u16><<<g, 256, 0, stream>>>(xb, W1b, h, h8, s1, cnt + s * 12, ltok + (size_t)s * 12 * CAP, lwgt + (size_t)s * 12 * CAP, desc + s * 96, ntl + s);
  }

  { // layer 2: out += sum over ranks of w * (gelu(h) @ W2[e]^T)   (bias already in out, f32)
    dim3 g(80, 8);
    int s;
    s = 3; moe_gemm<4096, 1024, true, false, float><<<g, 256, 0, stream>>>(h8, W2b, out, nullptr, s2, cnt + s * 12, ltok + (size_t)s * 12 * CAP, lwgt + (size_t)s * 12 * CAP, desc + s * 96, ntl + s);
    s = 4; moe_gemm<4096, 1024, true, false, float><<<g, 256, 0, stream>>>(h8, W2b, out, nullptr, s2, cnt + s * 12, ltok + (size_t)s * 12 * CAP, lwgt + (size_t)s * 12 * CAP, desc + s * 96, ntl + s);
    s = 5; moe_gemm<4096, 1024, true, false, float><<<g, 256, 0, stream>>>(h8, W2b, out, nullptr, s2, cnt + s * 12, ltok + (size_t)s * 12 * CAP, lwgt + (size_t)s * 12 * CAP, desc + s * 96, ntl + s);
  }
}